// Round 1
// baseline (1272.716 us; speedup 1.0000x reference)
//
#include <hip/hip_runtime.h>
#include <hip/hip_bf16.h>
#include <cstdint>

#define N_NODES_C 100000
#define IN_FEAT 512
#define HIDDEN 128
#define N_CLASSES 7

// ---------------------------------------------------------------- utilities
__global__ void k_zero_int(int* __restrict__ p, int n) {
    int i = blockIdx.x * blockDim.x + threadIdx.x;
    if (i < n) p[i] = 0;
}

// count[v] = number of edges with dst == v
__global__ void k_count(const int* __restrict__ dst, int* __restrict__ count, int E) {
    int i = blockIdx.x * blockDim.x + threadIdx.x;
    if (i < E) atomicAdd(&count[dst[i]], 1);
}

// single-block exclusive scan of count -> rowp/cursor, plus dinv = rsqrt(count+1)
__global__ __launch_bounds__(1024) void k_scan(const int* __restrict__ count,
                                               int* __restrict__ rowp,
                                               int* __restrict__ cursor,
                                               float* __restrict__ dinv, int N) {
    __shared__ int sums[1024];
    const int tid = threadIdx.x;
    const int chunk = (N + 1023) / 1024;
    const int beg = tid * chunk;
    const int end = min(beg + chunk, N);
    int s = 0;
    for (int i = beg; i < end; ++i) s += count[i];
    sums[tid] = s;
    __syncthreads();
    // Hillis-Steele inclusive scan
    for (int off = 1; off < 1024; off <<= 1) {
        int v = (tid >= off) ? sums[tid - off] : 0;
        __syncthreads();
        sums[tid] += v;
        __syncthreads();
    }
    int run = sums[tid] - s;  // exclusive prefix for this chunk
    for (int i = beg; i < end; ++i) {
        rowp[i] = run;
        cursor[i] = run;
        dinv[i] = rsqrtf((float)(count[i] + 1));  // +1 self loop
        run += count[i];
    }
    if (tid == 1023) rowp[N] = sums[1023];
}

// scatter edges into CSR (grouped by dst, storing src)
__global__ void k_fill(const int* __restrict__ src, const int* __restrict__ dst,
                       int* __restrict__ cursor, int* __restrict__ csr, int E) {
    int i = blockIdx.x * blockDim.x + threadIdx.x;
    if (i < E) {
        int pos = atomicAdd(&cursor[dst[i]], 1);
        csr[pos] = src[i];
    }
}

// ---------------------------------------------------------------- GEMM1
// C[M,128] = A[M,512] @ B[512,128], fp32 vector ALU, 128x128 tile, BK=32
#define G1_BM 128
#define G1_BN 128
#define G1_BK 32

__global__ __launch_bounds__(256) void k_gemm1(const float* __restrict__ A,
                                               const float* __restrict__ B,
                                               float* __restrict__ C, int M) {
    __shared__ float As[2][G1_BK][G1_BM];  // transposed: As[k][m]
    __shared__ float Bs[2][G1_BK][G1_BN];  // Bs[k][n]
    const int tid = threadIdx.x;
    const int tx = tid & 15;   // col group: cols tx*4..+3 and 64+tx*4..+3
    const int ty = tid >> 4;   // row group: rows ty*4..+3 and 64+ty*4..+3
    const int bm = blockIdx.x * G1_BM;

    const int a_row = tid >> 3;        // 0..31
    const int a_col = (tid & 7) * 4;   // k offset 0..28
    const int b_row = tid >> 5;        // 0..7
    const int b_col = (tid & 31) * 4;  // 0..124

    float acc[8][8];
    #pragma unroll
    for (int i = 0; i < 8; ++i)
        #pragma unroll
        for (int j = 0; j < 8; ++j) acc[i][j] = 0.f;

    auto load_tiles = [&](int kt, int buf) {
        const int k0 = kt * G1_BK;
        #pragma unroll
        for (int p = 0; p < 4; ++p) {
            int m = p * 32 + a_row;
            int gr = bm + m;
            float4 v = make_float4(0.f, 0.f, 0.f, 0.f);
            if (gr < M) v = *(const float4*)&A[(size_t)gr * IN_FEAT + k0 + a_col];
            As[buf][a_col + 0][m] = v.x;
            As[buf][a_col + 1][m] = v.y;
            As[buf][a_col + 2][m] = v.z;
            As[buf][a_col + 3][m] = v.w;
        }
        #pragma unroll
        for (int p = 0; p < 4; ++p) {
            int k = p * 8 + b_row;
            *(float4*)&Bs[buf][k][b_col] =
                *(const float4*)&B[(size_t)(k0 + k) * HIDDEN + b_col];
        }
    };

    load_tiles(0, 0);
    __syncthreads();
    const int KT = IN_FEAT / G1_BK;  // 16
    for (int kt = 0; kt < KT; ++kt) {
        const int buf = kt & 1;
        if (kt + 1 < KT) load_tiles(kt + 1, buf ^ 1);
        #pragma unroll
        for (int k = 0; k < G1_BK; ++k) {
            float4 a0 = *(const float4*)&As[buf][k][ty * 4];
            float4 a1 = *(const float4*)&As[buf][k][64 + ty * 4];
            float4 b0 = *(const float4*)&Bs[buf][k][tx * 4];
            float4 b1 = *(const float4*)&Bs[buf][k][64 + tx * 4];
            float ar[8] = {a0.x, a0.y, a0.z, a0.w, a1.x, a1.y, a1.z, a1.w};
            float br[8] = {b0.x, b0.y, b0.z, b0.w, b1.x, b1.y, b1.z, b1.w};
            #pragma unroll
            for (int i = 0; i < 8; ++i)
                #pragma unroll
                for (int j = 0; j < 8; ++j) acc[i][j] += ar[i] * br[j];
        }
        __syncthreads();
    }

    #pragma unroll
    for (int i = 0; i < 8; ++i) {
        int r = bm + ((i < 4) ? (ty * 4 + i) : (64 + ty * 4 + (i - 4)));
        if (r < M) {
            *(float4*)&C[(size_t)r * HIDDEN + tx * 4] =
                make_float4(acc[i][0], acc[i][1], acc[i][2], acc[i][3]);
            *(float4*)&C[(size_t)r * HIDDEN + 64 + tx * 4] =
                make_float4(acc[i][4], acc[i][5], acc[i][6], acc[i][7]);
        }
    }
}

// ---------------------------------------------------------------- Agg1
// h1[d] = relu( dinv[d]*sum_{e} t1[src_e]*dinv[src_e] + dinv[d]^2*t1[d] + b1 )
// one wave per node, lane handles 2 of 128 features
__global__ __launch_bounds__(256) void k_agg1(const float* __restrict__ t1,
                                              const int* __restrict__ csr,
                                              const int* __restrict__ rowp,
                                              const float* __restrict__ dinv,
                                              const float* __restrict__ b1,
                                              float* __restrict__ h1, int N) {
    const int node = blockIdx.x * 4 + (threadIdx.x >> 6);
    if (node >= N) return;
    const int lane = threadIdx.x & 63;
    const int beg = rowp[node], end = rowp[node + 1];
    float ax = 0.f, ay = 0.f;
    for (int e = beg; e < end; ++e) {
        int s = csr[e];
        float w = dinv[s];
        float2 row = *(const float2*)&t1[(size_t)s * HIDDEN + lane * 2];
        ax += row.x * w;
        ay += row.y * w;
    }
    float dd = dinv[node];
    float2 self = *(const float2*)&t1[(size_t)node * HIDDEN + lane * 2];
    float2 bb = *(const float2*)&b1[lane * 2];
    float ox = fmaxf(dd * ax + dd * dd * self.x + bb.x, 0.f);
    float oy = fmaxf(dd * ay + dd * dd * self.y + bb.y, 0.f);
    *(float2*)&h1[(size_t)node * HIDDEN + lane * 2] = make_float2(ox, oy);
}

// ---------------------------------------------------------------- GEMM2
// t2[N,7] = h1[N,128] @ W2[128,7]; one wave per row, shuffle-reduce
__global__ __launch_bounds__(256) void k_gemm2(const float* __restrict__ h1,
                                               const float* __restrict__ W2,
                                               float* __restrict__ t2, int N) {
    const int lane = threadIdx.x & 63;
    const int node = blockIdx.x * 4 + (threadIdx.x >> 6);
    float w0[N_CLASSES], w1[N_CLASSES];
    #pragma unroll
    for (int j = 0; j < N_CLASSES; ++j) {
        w0[j] = W2[(2 * lane) * N_CLASSES + j];
        w1[j] = W2[(2 * lane + 1) * N_CLASSES + j];
    }
    if (node >= N) return;
    float2 h = *(const float2*)&h1[(size_t)node * HIDDEN + lane * 2];
    float acc[N_CLASSES];
    #pragma unroll
    for (int j = 0; j < N_CLASSES; ++j) acc[j] = h.x * w0[j] + h.y * w1[j];
    #pragma unroll
    for (int off = 32; off >= 1; off >>= 1)
        #pragma unroll
        for (int j = 0; j < N_CLASSES; ++j) acc[j] += __shfl_xor(acc[j], off);
    if (lane == 0) {
        #pragma unroll
        for (int j = 0; j < N_CLASSES; ++j) t2[(size_t)node * N_CLASSES + j] = acc[j];
    }
}

// ---------------------------------------------------------------- Agg2
// out[d] = dinv[d]*sum t2[src]*dinv[src] + dinv[d]^2*t2[d] + b2; thread per node
__global__ __launch_bounds__(256) void k_agg2(const float* __restrict__ t2,
                                              const int* __restrict__ csr,
                                              const int* __restrict__ rowp,
                                              const float* __restrict__ dinv,
                                              const float* __restrict__ b2,
                                              float* __restrict__ out, int N) {
    const int node = blockIdx.x * blockDim.x + threadIdx.x;
    if (node >= N) return;
    float acc[N_CLASSES];
    #pragma unroll
    for (int j = 0; j < N_CLASSES; ++j) acc[j] = 0.f;
    const int beg = rowp[node], end = rowp[node + 1];
    for (int e = beg; e < end; ++e) {
        int s = csr[e];
        float w = dinv[s];
        const float* r = &t2[(size_t)s * N_CLASSES];
        #pragma unroll
        for (int j = 0; j < N_CLASSES; ++j) acc[j] += r[j] * w;
    }
    float dd = dinv[node];
    const float* sr = &t2[(size_t)node * N_CLASSES];
    #pragma unroll
    for (int j = 0; j < N_CLASSES; ++j)
        out[(size_t)node * N_CLASSES + j] = dd * acc[j] + dd * dd * sr[j] + b2[j];
}

// ---------------------------------------------------------------- launch
extern "C" void kernel_launch(void* const* d_in, const int* in_sizes, int n_in,
                              void* d_out, int out_size, void* d_ws, size_t ws_size,
                              hipStream_t stream) {
    const float* x  = (const float*)d_in[0];
    const int*   ei = (const int*)d_in[1];
    const float* W1 = (const float*)d_in[2];
    const float* b1 = (const float*)d_in[3];
    const float* W2 = (const float*)d_in[4];
    const float* b2 = (const float*)d_in[5];
    float* out = (float*)d_out;

    const int N = N_NODES_C;
    const int E = in_sizes[1] / 2;
    const int* src = ei;
    const int* dst = ei + E;

    // workspace carve-up (256B aligned slots)
    size_t off = 0;
    auto alloc = [&](size_t bytes) {
        void* p = (char*)d_ws + off;
        off += (bytes + 255) & ~(size_t)255;
        return p;
    };
    int*   count  = (int*)alloc((size_t)N * 4);
    int*   rowp   = (int*)alloc((size_t)(N + 1) * 4);
    int*   cursor = (int*)alloc((size_t)N * 4);
    int*   csr    = (int*)alloc((size_t)E * 4);
    float* dinv   = (float*)alloc((size_t)N * 4);
    float* t1     = (float*)alloc((size_t)N * HIDDEN * 4);
    float* h1     = (float*)alloc((size_t)N * HIDDEN * 4);
    float* t2     = (float*)alloc((size_t)N * N_CLASSES * 4);
    (void)ws_size;

    // 1. degree histogram
    k_zero_int<<<(N + 255) / 256, 256, 0, stream>>>(count, N);
    k_count<<<(E + 255) / 256, 256, 0, stream>>>(dst, count, E);
    // 2. scan -> rowp/cursor/dinv
    k_scan<<<1, 1024, 0, stream>>>(count, rowp, cursor, dinv, N);
    // 3. CSR fill
    k_fill<<<(E + 255) / 256, 256, 0, stream>>>(src, dst, cursor, csr, E);
    // 4. t1 = x @ W1
    k_gemm1<<<(N + G1_BM - 1) / G1_BM, 256, 0, stream>>>(x, W1, t1, N);
    // 5. h1 = relu(agg(t1) + b1)
    k_agg1<<<(N + 3) / 4, 256, 0, stream>>>(t1, csr, rowp, dinv, b1, h1, N);
    // 6. t2 = h1 @ W2
    k_gemm2<<<(N + 3) / 4, 256, 0, stream>>>(h1, W2, t2, N);
    // 7. out = agg(t2) + b2
    k_agg2<<<(N + 255) / 256, 256, 0, stream>>>(t2, csr, rowp, dinv, b2, out, N);
}

// Round 3
// 726.463 us; speedup vs baseline: 1.7519x; 1.7519x over previous
//
#include <hip/hip_runtime.h>
#include <hip/hip_bf16.h>
#include <cstdint>

#define N_NODES_C 100000
#define IN_FEAT 512
#define HIDDEN 128
#define N_CLASSES 7

using f16x8 = __attribute__((ext_vector_type(8))) _Float16;
using f32x4 = __attribute__((ext_vector_type(4))) float;

// ---------------------------------------------------------------- utilities
__global__ void k_zero_int(int* __restrict__ p, int n) {
    int i = blockIdx.x * blockDim.x + threadIdx.x;
    if (i < n) p[i] = 0;
}

// count[v] = number of edges with dst == v
__global__ void k_count(const int* __restrict__ dst, int* __restrict__ count, int E) {
    int i = blockIdx.x * blockDim.x + threadIdx.x;
    if (i < E) atomicAdd(&count[dst[i]], 1);
}

// partial[b] = sum of count[b*256 .. b*256+255]
__global__ __launch_bounds__(256) void k_partsum(const int* __restrict__ count,
                                                 int* __restrict__ partial, int N) {
    int i = blockIdx.x * 256 + threadIdx.x;
    int c = (i < N) ? count[i] : 0;
    #pragma unroll
    for (int off = 32; off >= 1; off >>= 1) c += __shfl_xor(c, off);
    __shared__ int ws[4];
    if ((threadIdx.x & 63) == 0) ws[threadIdx.x >> 6] = c;
    __syncthreads();
    if (threadIdx.x == 0) partial[blockIdx.x] = ws[0] + ws[1] + ws[2] + ws[3];
}

// single small block: exclusive scan of partial[NB] -> partoff; rowp[N] = total
__global__ __launch_bounds__(512) void k_scan_part(const int* __restrict__ partial,
                                                   int* __restrict__ partoff,
                                                   int* __restrict__ rowp, int NB, int N) {
    __shared__ int s[512];
    int t = threadIdx.x;
    int v = (t < NB) ? partial[t] : 0;
    s[t] = v;
    __syncthreads();
    for (int off = 1; off < 512; off <<= 1) {
        int u = (t >= off) ? s[t - off] : 0;
        __syncthreads();
        s[t] += u;
        __syncthreads();
    }
    if (t < NB) partoff[t] = s[t] - v;
    if (t == 511) rowp[N] = s[511];
}

// coalesced block-level scan: rowp/cursor/dinv
__global__ __launch_bounds__(256) void k_scan_final(const int* __restrict__ count,
                                                    const int* __restrict__ partoff,
                                                    int* __restrict__ rowp,
                                                    int* __restrict__ cursor,
                                                    float* __restrict__ dinv, int N) {
    __shared__ int wsum[4];
    int i = blockIdx.x * 256 + threadIdx.x;
    int lane = threadIdx.x & 63, w = threadIdx.x >> 6;
    int c = (i < N) ? count[i] : 0;
    int x = c;
    #pragma unroll
    for (int off = 1; off < 64; off <<= 1) {
        int v = __shfl_up(x, off);
        if (lane >= off) x += v;
    }
    if (lane == 63) wsum[w] = x;
    __syncthreads();
    int woff = 0;
    #pragma unroll
    for (int k = 0; k < 4; ++k)
        if (k < w) woff += wsum[k];
    int excl = partoff[blockIdx.x] + woff + x - c;
    if (i < N) {
        rowp[i] = excl;
        cursor[i] = excl;
        dinv[i] = rsqrtf((float)(c + 1));  // +1 self loop
    }
}

// scatter edges into CSR (grouped by dst, storing src)
__global__ void k_fill(const int* __restrict__ src, const int* __restrict__ dst,
                       int* __restrict__ cursor, int* __restrict__ csr, int E) {
    int i = blockIdx.x * blockDim.x + threadIdx.x;
    if (i < E) {
        int pos = atomicAdd(&cursor[dst[i]], 1);
        csr[pos] = src[i];
    }
}

// ---------------------------------------------------------------- W1 prep
// W1 [512][128] fp32 -> W1T [128][512] f16
__global__ __launch_bounds__(256) void k_prep_w1(const float* __restrict__ W1,
                                                 _Float16* __restrict__ W1T) {
    __shared__ _Float16 tile[16][128];
    const int k0 = blockIdx.x * 16;
    const int t = threadIdx.x;
    #pragma unroll
    for (int i = 0; i < 8; ++i) {
        int idx = i * 256 + t;
        int k = idx >> 7, n = idx & 127;
        tile[k][n] = (_Float16)W1[(size_t)(k0 + k) * HIDDEN + n];
    }
    __syncthreads();
    int n = t >> 1, kh = (t & 1) * 8;
    _Float16 tmp[8];
    #pragma unroll
    for (int i = 0; i < 8; ++i) tmp[i] = tile[kh + i][n];
    *(uint4*)&W1T[(size_t)n * IN_FEAT + k0 + kh] = *(const uint4*)tmp;
}

// ---------------------------------------------------------------- GEMM1 (f16 MFMA)
// t1s[M][128] = (x @ W1) * dinv[row].  LDS-free: each wave owns 32 rows x 128 cols.
__global__ __launch_bounds__(256) void k_gemm1(const float* __restrict__ A,
                                               const _Float16* __restrict__ BT,
                                               const float* __restrict__ dinv,
                                               float* __restrict__ t1s, int M) {
    const int wid = threadIdx.x >> 6;
    const int lane = threadIdx.x & 63;
    const int row0 = blockIdx.x * 128 + wid * 32;
    const int r = lane & 15;        // row/col within fragment
    const int kb = lane >> 4;       // k-block 0..3

    f32x4 acc[2][8];
    #pragma unroll
    for (int m = 0; m < 2; ++m)
        #pragma unroll
        for (int j = 0; j < 8; ++j) acc[m][j] = (f32x4){0.f, 0.f, 0.f, 0.f};

    for (int ks = 0; ks < IN_FEAT / 32; ++ks) {
        const int kofs = ks * 32 + kb * 8;
        // A fragments: rows row0 + m*16 + r, 8 contiguous k (fp32 -> f16)
        f16x8 a[2];
        #pragma unroll
        for (int m = 0; m < 2; ++m) {
            int ra = row0 + m * 16 + r;
            float4 v0 = make_float4(0.f, 0.f, 0.f, 0.f), v1 = v0;
            if (ra < M) {
                const float* p = &A[(size_t)ra * IN_FEAT + kofs];
                v0 = *(const float4*)p;
                v1 = *(const float4*)(p + 4);
            }
            a[m][0] = (_Float16)v0.x; a[m][1] = (_Float16)v0.y;
            a[m][2] = (_Float16)v0.z; a[m][3] = (_Float16)v0.w;
            a[m][4] = (_Float16)v1.x; a[m][5] = (_Float16)v1.y;
            a[m][6] = (_Float16)v1.z; a[m][7] = (_Float16)v1.w;
        }
        // B fragments: col j*16 + r, 8 contiguous k (pre-converted f16, L2-resident)
        #pragma unroll
        for (int j = 0; j < 8; ++j) {
            f16x8 b = *(const f16x8*)&BT[(size_t)(j * 16 + r) * IN_FEAT + kofs];
            #pragma unroll
            for (int m = 0; m < 2; ++m)
                acc[m][j] = __builtin_amdgcn_mfma_f32_16x16x32_f16(a[m], b, acc[m][j], 0, 0, 0);
        }
    }

    // C/D layout: col = lane&15, row = (lane>>4)*4 + i
    #pragma unroll
    for (int m = 0; m < 2; ++m) {
        #pragma unroll
        for (int i = 0; i < 4; ++i) {
            int rr = row0 + m * 16 + kb * 4 + i;
            if (rr < M) {
                float dd = dinv[rr];
                #pragma unroll
                for (int j = 0; j < 8; ++j)
                    t1s[(size_t)rr * HIDDEN + j * 16 + r] = acc[m][j][i] * dd;
            }
        }
    }
}

// ---------------------------------------------------------------- Agg1 + GEMM2 fused
// h = relu(dinv[d]*(sum t1s[src] + t1s[d]) + b1);  t2s[d] = (h @ W2) * dinv[d]
// one wave per node; lane holds 2 of 128 features
__global__ __launch_bounds__(256) void k_agg1(const float* __restrict__ t1s,
                                              const int* __restrict__ csr,
                                              const int* __restrict__ rowp,
                                              const float* __restrict__ dinv,
                                              const float* __restrict__ b1,
                                              const float* __restrict__ W2,
                                              float* __restrict__ t2s, int N) {
    const int node = blockIdx.x * 4 + (threadIdx.x >> 6);
    if (node >= N) return;
    const int lane = threadIdx.x & 63;
    const int beg = rowp[node], end = rowp[node + 1];
    float ax = 0.f, ay = 0.f;
    for (int e = beg; e < end; ++e) {
        int s = csr[e];
        float2 row = *(const float2*)&t1s[(size_t)s * HIDDEN + lane * 2];
        ax += row.x;
        ay += row.y;
    }
    const float dd = dinv[node];
    float2 self = *(const float2*)&t1s[(size_t)node * HIDDEN + lane * 2];
    float2 bb = *(const float2*)&b1[lane * 2];
    float hx = fmaxf(dd * (ax + self.x) + bb.x, 0.f);
    float hy = fmaxf(dd * (ay + self.y) + bb.y, 0.f);
    // project to 7 classes: per-lane partial, butterfly reduce over 64 lanes
    float acc[N_CLASSES];
    #pragma unroll
    for (int j = 0; j < N_CLASSES; ++j)
        acc[j] = hx * W2[(2 * lane) * N_CLASSES + j] + hy * W2[(2 * lane + 1) * N_CLASSES + j];
    #pragma unroll
    for (int off = 32; off >= 1; off >>= 1)
        #pragma unroll
        for (int j = 0; j < N_CLASSES; ++j) acc[j] += __shfl_xor(acc[j], off);
    if (lane == 0) {
        #pragma unroll
        for (int j = 0; j < N_CLASSES; ++j)
            t2s[(size_t)node * N_CLASSES + j] = acc[j] * dd;
    }
}

// ---------------------------------------------------------------- Agg2
// out[d][j] = dinv[d]*(sum t2s[src] + t2s[d]) + b2[j]; 8 lanes per node (j-parallel)
__global__ __launch_bounds__(256) void k_agg2(const float* __restrict__ t2s,
                                              const int* __restrict__ csr,
                                              const int* __restrict__ rowp,
                                              const float* __restrict__ dinv,
                                              const float* __restrict__ b2,
                                              float* __restrict__ out, int N) {
    const int node = blockIdx.x * 32 + (threadIdx.x >> 3);
    const int j = threadIdx.x & 7;
    if (node >= N || j >= N_CLASSES) return;
    const int beg = rowp[node], end = rowp[node + 1];
    float acc = 0.f;
    for (int e = beg; e < end; ++e) {
        int s = csr[e];
        acc += t2s[(size_t)s * N_CLASSES + j];
    }
    float dd = dinv[node];
    out[(size_t)node * N_CLASSES + j] =
        dd * (acc + t2s[(size_t)node * N_CLASSES + j]) + b2[j];
}

// ---------------------------------------------------------------- launch
extern "C" void kernel_launch(void* const* d_in, const int* in_sizes, int n_in,
                              void* d_out, int out_size, void* d_ws, size_t ws_size,
                              hipStream_t stream) {
    const float* x  = (const float*)d_in[0];
    const int*   ei = (const int*)d_in[1];
    const float* W1 = (const float*)d_in[2];
    const float* b1 = (const float*)d_in[3];
    const float* W2 = (const float*)d_in[4];
    const float* b2 = (const float*)d_in[5];
    float* out = (float*)d_out;

    const int N = N_NODES_C;
    const int E = in_sizes[1] / 2;
    const int* src = ei;
    const int* dst = ei + E;
    const int NB = (N + 255) / 256;  // 391 scan blocks

    size_t off = 0;
    auto alloc = [&](size_t bytes) {
        void* p = (char*)d_ws + off;
        off += (bytes + 255) & ~(size_t)255;
        return p;
    };
    int*      count   = (int*)alloc((size_t)N * 4);
    int*      rowp    = (int*)alloc((size_t)(N + 1) * 4);
    int*      cursor  = (int*)alloc((size_t)N * 4);
    int*      csr     = (int*)alloc((size_t)E * 4);
    float*    dinv    = (float*)alloc((size_t)N * 4);
    int*      partial = (int*)alloc((size_t)512 * 4);
    int*      partoff = (int*)alloc((size_t)512 * 4);
    _Float16* W1T     = (_Float16*)alloc((size_t)HIDDEN * IN_FEAT * 2);
    float*    t1s     = (float*)alloc((size_t)N * HIDDEN * 4);
    float*    t2s     = (float*)alloc((size_t)N * N_CLASSES * 4);
    (void)ws_size;

    // degree histogram + coalesced 3-phase scan + CSR fill
    k_zero_int<<<(N + 255) / 256, 256, 0, stream>>>(count, N);
    k_count<<<(E + 255) / 256, 256, 0, stream>>>(dst, count, E);
    k_partsum<<<NB, 256, 0, stream>>>(count, partial, N);
    k_scan_part<<<1, 512, 0, stream>>>(partial, partoff, rowp, NB, N);
    k_scan_final<<<NB, 256, 0, stream>>>(count, partoff, rowp, cursor, dinv, N);
    k_fill<<<(E + 255) / 256, 256, 0, stream>>>(src, dst, cursor, csr, E);
    // W1 -> f16 transposed
    k_prep_w1<<<IN_FEAT / 16, 256, 0, stream>>>(W1, W1T);
    // t1s = (x @ W1) * dinv
    k_gemm1<<<(N + 127) / 128, 256, 0, stream>>>(x, W1T, dinv, t1s, N);
    // fused agg1 + relu + gemm2 -> t2s
    k_agg1<<<(N + 3) / 4, 256, 0, stream>>>(t1s, csr, rowp, dinv, b1, W2, t2s, N);
    // out = agg(t2s) + b2
    k_agg2<<<(N + 31) / 32, 256, 0, stream>>>(t2s, csr, rowp, dinv, b2, out, N);
}

// Round 4
// 644.637 us; speedup vs baseline: 1.9743x; 1.1269x over previous
//
#include <hip/hip_runtime.h>
#include <hip/hip_bf16.h>
#include <cstdint>

#define N_NODES_C 100000
#define IN_FEAT 512
#define HIDDEN 128
#define N_CLASSES 7
#define T2_STRIDE 8

using f16x8 = __attribute__((ext_vector_type(8))) _Float16;
using f16x2 = __attribute__((ext_vector_type(2))) _Float16;
using f32x4 = __attribute__((ext_vector_type(4))) float;

// ---------------------------------------------------------------- utilities
__global__ void k_zero_int(int* __restrict__ p, int n) {
    int i = blockIdx.x * blockDim.x + threadIdx.x;
    if (i < n) p[i] = 0;
}

// count[v] = number of edges with dst == v
__global__ void k_count(const int* __restrict__ dst, int* __restrict__ count, int E) {
    int i = blockIdx.x * blockDim.x + threadIdx.x;
    if (i < E) atomicAdd(&count[dst[i]], 1);
}

// partial[b] = sum of count[b*256 .. b*256+255]
__global__ __launch_bounds__(256) void k_partsum(const int* __restrict__ count,
                                                 int* __restrict__ partial, int N) {
    int i = blockIdx.x * 256 + threadIdx.x;
    int c = (i < N) ? count[i] : 0;
    #pragma unroll
    for (int off = 32; off >= 1; off >>= 1) c += __shfl_xor(c, off);
    __shared__ int ws[4];
    if ((threadIdx.x & 63) == 0) ws[threadIdx.x >> 6] = c;
    __syncthreads();
    if (threadIdx.x == 0) partial[blockIdx.x] = ws[0] + ws[1] + ws[2] + ws[3];
}

// single small block: exclusive scan of partial[NB] -> partoff; rowp[N] = total
__global__ __launch_bounds__(512) void k_scan_part(const int* __restrict__ partial,
                                                   int* __restrict__ partoff,
                                                   int* __restrict__ rowp, int NB, int N) {
    __shared__ int s[512];
    int t = threadIdx.x;
    int v = (t < NB) ? partial[t] : 0;
    s[t] = v;
    __syncthreads();
    for (int off = 1; off < 512; off <<= 1) {
        int u = (t >= off) ? s[t - off] : 0;
        __syncthreads();
        s[t] += u;
        __syncthreads();
    }
    if (t < NB) partoff[t] = s[t] - v;
    if (t == 511) rowp[N] = s[511];
}

// coalesced block-level scan: rowp/cursor/dinv
__global__ __launch_bounds__(256) void k_scan_final(const int* __restrict__ count,
                                                    const int* __restrict__ partoff,
                                                    int* __restrict__ rowp,
                                                    int* __restrict__ cursor,
                                                    float* __restrict__ dinv, int N) {
    __shared__ int wsum[4];
    int i = blockIdx.x * 256 + threadIdx.x;
    int lane = threadIdx.x & 63, w = threadIdx.x >> 6;
    int c = (i < N) ? count[i] : 0;
    int x = c;
    #pragma unroll
    for (int off = 1; off < 64; off <<= 1) {
        int v = __shfl_up(x, off);
        if (lane >= off) x += v;
    }
    if (lane == 63) wsum[w] = x;
    __syncthreads();
    int woff = 0;
    #pragma unroll
    for (int k = 0; k < 4; ++k)
        if (k < w) woff += wsum[k];
    int excl = partoff[blockIdx.x] + woff + x - c;
    if (i < N) {
        rowp[i] = excl;
        cursor[i] = excl;
        dinv[i] = rsqrtf((float)(c + 1));  // +1 self loop
    }
}

// scatter edges into CSR (grouped by dst, storing src)
__global__ void k_fill(const int* __restrict__ src, const int* __restrict__ dst,
                       int* __restrict__ cursor, int* __restrict__ csr, int E) {
    int i = blockIdx.x * blockDim.x + threadIdx.x;
    if (i < E) {
        int pos = atomicAdd(&cursor[dst[i]], 1);
        csr[pos] = src[i];
    }
}

// ---------------------------------------------------------------- W1 prep
// W1 [512][128] fp32 -> W1T [128][512] f16
__global__ __launch_bounds__(256) void k_prep_w1(const float* __restrict__ W1,
                                                 _Float16* __restrict__ W1T) {
    __shared__ _Float16 tile[16][128];
    const int k0 = blockIdx.x * 16;
    const int t = threadIdx.x;
    #pragma unroll
    for (int i = 0; i < 8; ++i) {
        int idx = i * 256 + t;
        int k = idx >> 7, n = idx & 127;
        tile[k][n] = (_Float16)W1[(size_t)(k0 + k) * HIDDEN + n];
    }
    __syncthreads();
    int n = t >> 1, kh = (t & 1) * 8;
    _Float16 tmp[8];
    #pragma unroll
    for (int i = 0; i < 8; ++i) tmp[i] = tile[kh + i][n];
    *(uint4*)&W1T[(size_t)n * IN_FEAT + k0 + kh] = *(const uint4*)tmp;
}

// ---------------------------------------------------------------- GEMM1 (f16 MFMA)
// t1h[M][128] (f16) = (x @ W1) * dinv[row].  LDS-free: each wave owns 32 rows.
__global__ __launch_bounds__(256) void k_gemm1(const float* __restrict__ A,
                                               const _Float16* __restrict__ BT,
                                               const float* __restrict__ dinv,
                                               _Float16* __restrict__ t1h, int M) {
    const int wid = threadIdx.x >> 6;
    const int lane = threadIdx.x & 63;
    const int row0 = blockIdx.x * 128 + wid * 32;
    const int r = lane & 15;        // row/col within fragment
    const int kb = lane >> 4;       // k-block 0..3

    f32x4 acc[2][8];
    #pragma unroll
    for (int m = 0; m < 2; ++m)
        #pragma unroll
        for (int j = 0; j < 8; ++j) acc[m][j] = (f32x4){0.f, 0.f, 0.f, 0.f};

    for (int ks = 0; ks < IN_FEAT / 32; ++ks) {
        const int kofs = ks * 32 + kb * 8;
        f16x8 a[2];
        #pragma unroll
        for (int m = 0; m < 2; ++m) {
            int ra = row0 + m * 16 + r;
            float4 v0 = make_float4(0.f, 0.f, 0.f, 0.f), v1 = v0;
            if (ra < M) {
                const float* p = &A[(size_t)ra * IN_FEAT + kofs];
                v0 = *(const float4*)p;
                v1 = *(const float4*)(p + 4);
            }
            a[m][0] = (_Float16)v0.x; a[m][1] = (_Float16)v0.y;
            a[m][2] = (_Float16)v0.z; a[m][3] = (_Float16)v0.w;
            a[m][4] = (_Float16)v1.x; a[m][5] = (_Float16)v1.y;
            a[m][6] = (_Float16)v1.z; a[m][7] = (_Float16)v1.w;
        }
        #pragma unroll
        for (int j = 0; j < 8; ++j) {
            f16x8 b = *(const f16x8*)&BT[(size_t)(j * 16 + r) * IN_FEAT + kofs];
            #pragma unroll
            for (int m = 0; m < 2; ++m)
                acc[m][j] = __builtin_amdgcn_mfma_f32_16x16x32_f16(a[m], b, acc[m][j], 0, 0, 0);
        }
    }

    // C/D layout: col = lane&15, row = (lane>>4)*4 + i
    #pragma unroll
    for (int m = 0; m < 2; ++m) {
        #pragma unroll
        for (int i = 0; i < 4; ++i) {
            int rr = row0 + m * 16 + kb * 4 + i;
            if (rr < M) {
                float dd = dinv[rr];
                #pragma unroll
                for (int j = 0; j < 8; ++j)
                    t1h[(size_t)rr * HIDDEN + j * 16 + r] = (_Float16)(acc[m][j][i] * dd);
            }
        }
    }
}

// ---------------------------------------------------------------- Agg1 + GEMM2 fused
// h = relu(dinv[d]*(sum t1h[src] + t1h[d]) + b1);  t2s[d] = (h @ W2) * dinv[d]
// one wave per node; lane holds 2 of 128 features; 8-deep edge unroll for MLP
__global__ __launch_bounds__(256) void k_agg1(const _Float16* __restrict__ t1h,
                                              const int* __restrict__ csr,
                                              const int* __restrict__ rowp,
                                              const float* __restrict__ dinv,
                                              const float* __restrict__ b1,
                                              const float* __restrict__ W2,
                                              float* __restrict__ t2s, int N) {
    const int node = blockIdx.x * 4 + (threadIdx.x >> 6);
    if (node >= N) return;
    const int lane = threadIdx.x & 63;
    const int beg = rowp[node], end = rowp[node + 1];
    float ax = 0.f, ay = 0.f;
    int e = beg;
    for (; e + 8 <= end; e += 8) {
        int s0 = csr[e + 0], s1 = csr[e + 1], s2 = csr[e + 2], s3 = csr[e + 3];
        int s4 = csr[e + 4], s5 = csr[e + 5], s6 = csr[e + 6], s7 = csr[e + 7];
        f16x2 v0 = *(const f16x2*)&t1h[(size_t)s0 * HIDDEN + lane * 2];
        f16x2 v1 = *(const f16x2*)&t1h[(size_t)s1 * HIDDEN + lane * 2];
        f16x2 v2 = *(const f16x2*)&t1h[(size_t)s2 * HIDDEN + lane * 2];
        f16x2 v3 = *(const f16x2*)&t1h[(size_t)s3 * HIDDEN + lane * 2];
        f16x2 v4 = *(const f16x2*)&t1h[(size_t)s4 * HIDDEN + lane * 2];
        f16x2 v5 = *(const f16x2*)&t1h[(size_t)s5 * HIDDEN + lane * 2];
        f16x2 v6 = *(const f16x2*)&t1h[(size_t)s6 * HIDDEN + lane * 2];
        f16x2 v7 = *(const f16x2*)&t1h[(size_t)s7 * HIDDEN + lane * 2];
        ax += (float)v0.x + (float)v1.x + (float)v2.x + (float)v3.x
            + (float)v4.x + (float)v5.x + (float)v6.x + (float)v7.x;
        ay += (float)v0.y + (float)v1.y + (float)v2.y + (float)v3.y
            + (float)v4.y + (float)v5.y + (float)v6.y + (float)v7.y;
    }
    for (; e < end; ++e) {
        int s = csr[e];
        f16x2 v = *(const f16x2*)&t1h[(size_t)s * HIDDEN + lane * 2];
        ax += (float)v.x;
        ay += (float)v.y;
    }
    const float dd = dinv[node];
    f16x2 self = *(const f16x2*)&t1h[(size_t)node * HIDDEN + lane * 2];
    float2 bb = *(const float2*)&b1[lane * 2];
    float hx = fmaxf(dd * (ax + (float)self.x) + bb.x, 0.f);
    float hy = fmaxf(dd * (ay + (float)self.y) + bb.y, 0.f);
    // project to 7 classes: per-lane partial, butterfly reduce over 64 lanes
    float acc[N_CLASSES];
    #pragma unroll
    for (int j = 0; j < N_CLASSES; ++j)
        acc[j] = hx * W2[(2 * lane) * N_CLASSES + j] + hy * W2[(2 * lane + 1) * N_CLASSES + j];
    #pragma unroll
    for (int off = 32; off >= 1; off >>= 1)
        #pragma unroll
        for (int j = 0; j < N_CLASSES; ++j) acc[j] += __shfl_xor(acc[j], off);
    if (lane == 0) {
        float* row = &t2s[(size_t)node * T2_STRIDE];
        *(float4*)row = make_float4(acc[0] * dd, acc[1] * dd, acc[2] * dd, acc[3] * dd);
        *(float4*)(row + 4) = make_float4(acc[4] * dd, acc[5] * dd, acc[6] * dd, 0.f);
    }
}

// ---------------------------------------------------------------- Agg2
// out[d][j] = dinv[d]*(sum t2s[src] + t2s[d]) + b2[j]; 8 lanes per node (j-parallel)
__global__ __launch_bounds__(256) void k_agg2(const float* __restrict__ t2s,
                                              const int* __restrict__ csr,
                                              const int* __restrict__ rowp,
                                              const float* __restrict__ dinv,
                                              const float* __restrict__ b2,
                                              float* __restrict__ out, int N) {
    const int node = blockIdx.x * 32 + (threadIdx.x >> 3);
    const int j = threadIdx.x & 7;
    if (node >= N) return;
    const int beg = rowp[node], end = rowp[node + 1];
    float acc = 0.f;
    int e = beg;
    for (; e + 4 <= end; e += 4) {
        int s0 = csr[e + 0], s1 = csr[e + 1], s2 = csr[e + 2], s3 = csr[e + 3];
        float a0 = t2s[(size_t)s0 * T2_STRIDE + j];
        float a1 = t2s[(size_t)s1 * T2_STRIDE + j];
        float a2 = t2s[(size_t)s2 * T2_STRIDE + j];
        float a3 = t2s[(size_t)s3 * T2_STRIDE + j];
        acc += (a0 + a1) + (a2 + a3);
    }
    for (; e < end; ++e)
        acc += t2s[(size_t)csr[e] * T2_STRIDE + j];
    if (j < N_CLASSES) {
        float dd = dinv[node];
        out[(size_t)node * N_CLASSES + j] =
            dd * (acc + t2s[(size_t)node * T2_STRIDE + j]) + b2[j];
    }
}

// ---------------------------------------------------------------- launch
extern "C" void kernel_launch(void* const* d_in, const int* in_sizes, int n_in,
                              void* d_out, int out_size, void* d_ws, size_t ws_size,
                              hipStream_t stream) {
    const float* x  = (const float*)d_in[0];
    const int*   ei = (const int*)d_in[1];
    const float* W1 = (const float*)d_in[2];
    const float* b1 = (const float*)d_in[3];
    const float* W2 = (const float*)d_in[4];
    const float* b2 = (const float*)d_in[5];
    float* out = (float*)d_out;

    const int N = N_NODES_C;
    const int E = in_sizes[1] / 2;
    const int* src = ei;
    const int* dst = ei + E;
    const int NB = (N + 255) / 256;  // 391 scan blocks

    size_t off = 0;
    auto alloc = [&](size_t bytes) {
        void* p = (char*)d_ws + off;
        off += (bytes + 255) & ~(size_t)255;
        return p;
    };
    int*      count   = (int*)alloc((size_t)N * 4);
    int*      rowp    = (int*)alloc((size_t)(N + 1) * 4);
    int*      cursor  = (int*)alloc((size_t)N * 4);
    int*      csr     = (int*)alloc((size_t)E * 4);
    float*    dinv    = (float*)alloc((size_t)N * 4);
    int*      partial = (int*)alloc((size_t)512 * 4);
    int*      partoff = (int*)alloc((size_t)512 * 4);
    _Float16* W1T     = (_Float16*)alloc((size_t)HIDDEN * IN_FEAT * 2);
    _Float16* t1h     = (_Float16*)alloc((size_t)N * HIDDEN * 2);
    float*    t2s     = (float*)alloc((size_t)N * T2_STRIDE * 4);
    (void)ws_size;

    // degree histogram + coalesced 3-phase scan + CSR fill
    k_zero_int<<<(N + 255) / 256, 256, 0, stream>>>(count, N);
    k_count<<<(E + 255) / 256, 256, 0, stream>>>(dst, count, E);
    k_partsum<<<NB, 256, 0, stream>>>(count, partial, N);
    k_scan_part<<<1, 512, 0, stream>>>(partial, partoff, rowp, NB, N);
    k_scan_final<<<NB, 256, 0, stream>>>(count, partoff, rowp, cursor, dinv, N);
    k_fill<<<(E + 255) / 256, 256, 0, stream>>>(src, dst, cursor, csr, E);
    // W1 -> f16 transposed
    k_prep_w1<<<IN_FEAT / 16, 256, 0, stream>>>(W1, W1T);
    // t1h = (x @ W1) * dinv   (f16)
    k_gemm1<<<(N + 127) / 128, 256, 0, stream>>>(x, W1T, dinv, t1h, N);
    // fused agg1 + relu + gemm2 -> t2s (padded stride 8)
    k_agg1<<<(N + 3) / 4, 256, 0, stream>>>(t1h, csr, rowp, dinv, b1, W2, t2s, N);
    // out = agg(t2s) + b2
    k_agg2<<<(N + 31) / 32, 256, 0, stream>>>(t2s, csr, rowp, dinv, b2, out, N);
}